// Round 7
// baseline (170.846 us; speedup 1.0000x reference)
//
#include <hip/hip_runtime.h>
#include <hip/hip_bf16.h>
#include <stdint.h>

#define Bdim 32
#define Tdim 128
#define Fdim 2048
#define Mdim (Bdim*Tdim)   // 4096

#define BM 128
#define BN 64
#define BK 64

typedef __attribute__((ext_vector_type(8))) short bf16x8;
typedef __attribute__((ext_vector_type(4))) float f32x4;

__device__ inline unsigned short f2bf(float f) {
    union { float f; unsigned u; } x; x.f = f;
    unsigned r = (x.u + 0x7fffu + ((x.u >> 16) & 1u)) >> 16;   // RNE
    return (unsigned short)r;
}

// ---------------- kernel 1: fp32 -> bf16 convert (input and W) ----------------
__global__ void convert_kernel(const float* __restrict__ A, const float* __restrict__ W,
                               unsigned short* __restrict__ a16, unsigned short* __restrict__ w16) {
    const int nA4 = (Mdim * Fdim) / 4;   // 2097152
    const int nW4 = (Fdim * Fdim) / 4;   // 1048576
    const int stride = gridDim.x * blockDim.x;
    for (int i = blockIdx.x * blockDim.x + threadIdx.x; i < nA4 + nW4; i += stride) {
        const float4* src; unsigned short* dst; int j;
        if (i < nA4) { src = (const float4*)A; dst = a16; j = i; }
        else         { src = (const float4*)W; dst = w16; j = i - nA4; }
        float4 v = src[j];
        ushort4 o;
        o.x = f2bf(v.x); o.y = f2bf(v.y); o.z = f2bf(v.z); o.w = f2bf(v.w);
        *(ushort4*)(dst + 4 * (size_t)j) = o;
    }
}

// ---------------- kernel 2: bf16 MFMA GEMM, 128x64 tile, BK=64, dbuf + T2 swizzle ------
// C[M,N] = A[M,K] * W[N,K]^T   (both K-major), C fp32
// 1024 blocks -> 4/CU by grid, 3/CU by LDS (48KB): 12 waves/CU vs R6's 8.
// Swizzle: row = 8 chunks of 16B; data chunk c of row r lives at slot c^(r&7).
// Stage keeps LDS dest LINEAR (global_load_lds reqt), pre-permutes GLOBAL source;
// ds_read applies the same XOR (rule #21). Measured 0 conflicts in R6.
__global__ __launch_bounds__(256) void gemm_kernel(const unsigned short* __restrict__ A,
                                                   const unsigned short* __restrict__ Wm,
                                                   float* __restrict__ C) {
    __shared__ __align__(16) unsigned short sA[2][BM * BK];   // 2 x 16KB
    __shared__ __align__(16) unsigned short sB[2][BN * BK];   // 2 x  8KB

    const int tid = threadIdx.x;
    const int wid = tid >> 6, lane = tid & 63;
    const int wr = wid >> 1, wc = wid & 1;          // wave -> 64x32 sub-tile
    const int m0 = blockIdx.y * BM, n0 = blockIdx.x * BN;

    f32x4 acc[4][2];
#pragma unroll
    for (int i = 0; i < 4; i++)
#pragma unroll
        for (int j = 0; j < 2; j++) acc[i][j] = f32x4{0.f, 0.f, 0.f, 0.f};

    const int frow = lane & 15;
    const int lgrp = lane >> 4;                     // 0..3: k-slot group

    // stage A (16KB, 4 chunks) and B (8KB, 2 chunks) for K-step kt into buffer buf
    auto stage = [&](int buf, int kt) {
        const int k0 = kt * BK;
#pragma unroll
        for (int j = 0; j < 4; ++j) {
            const int base = wid * 1024 + j * 4096;   // wave-uniform byte base in 16KB A tile
            const int off  = base + lane * 16;
            const int row  = off >> 7;                // 128B per tile row
            const int chk  = (off & 127) >> 4;
            const int scol = ((chk ^ (row & 7)) << 3);
            const unsigned short* ga = A + (size_t)(m0 + row) * Fdim + k0 + scol;
            __builtin_amdgcn_global_load_lds(
                (const __attribute__((address_space(1))) void*)ga,
                (__attribute__((address_space(3))) void*)((char*)&sA[buf][0] + base),
                16, 0, 0);
        }
#pragma unroll
        for (int j = 0; j < 2; ++j) {
            const int base = wid * 1024 + j * 4096;   // byte base in 8KB B tile
            const int off  = base + lane * 16;
            const int row  = off >> 7;                // 0..63
            const int chk  = (off & 127) >> 4;
            const int scol = ((chk ^ (row & 7)) << 3);
            const unsigned short* gb = Wm + (size_t)(n0 + row) * Fdim + k0 + scol;
            __builtin_amdgcn_global_load_lds(
                (const __attribute__((address_space(1))) void*)gb,
                (__attribute__((address_space(3))) void*)((char*)&sB[buf][0] + base),
                16, 0, 0);
        }
    };

    stage(0, 0);
    __syncthreads();                                  // drains vmcnt(0): buf0 ready

    int cur = 0;
    const int NT = Fdim / BK;                         // 32
    for (int kt = 0; kt < NT; ++kt) {
        if (kt + 1 < NT) stage(cur ^ 1, kt + 1);      // async prefetch overlaps compute

        bf16x8 af[2][4], bfr[2][2];
#pragma unroll
        for (int kk = 0; kk < 2; kk++) {
            const int chunk = kk * 4 + lgrp;          // 16B chunk this lane consumes
#pragma unroll
            for (int mi = 0; mi < 4; mi++) {
                const int r = wr * 64 + mi * 16 + frow;
                af[kk][mi] = *(const bf16x8*)(&sA[cur][0] + r * BK + ((chunk ^ (r & 7)) << 3));
            }
#pragma unroll
            for (int ni = 0; ni < 2; ni++) {
                const int r = wc * 32 + ni * 16 + frow;
                bfr[kk][ni] = *(const bf16x8*)(&sB[cur][0] + r * BK + ((chunk ^ (r & 7)) << 3));
            }
        }
#pragma unroll
        for (int kk = 0; kk < 2; kk++)
#pragma unroll
            for (int mi = 0; mi < 4; mi++)
#pragma unroll
                for (int ni = 0; ni < 2; ni++)
                    acc[mi][ni] = __builtin_amdgcn_mfma_f32_16x16x32_bf16(af[kk][mi], bfr[kk][ni], acc[mi][ni], 0, 0, 0);

        __syncthreads();   // full drain: prefetch landed, all reads of `cur` done
        cur ^= 1;
    }

    // epilogue: verified C/D mapping col=lane&15, row=(lane>>4)*4+r
    const int crow = m0 + wr * 64 + (lane >> 4) * 4;
    const int ccol = n0 + wc * 32 + (lane & 15);
#pragma unroll
    for (int mi = 0; mi < 4; mi++)
#pragma unroll
        for (int ni = 0; ni < 2; ni++) {
            float* cp = C + (size_t)(crow + mi * 16) * Fdim + ccol + ni * 16;
#pragma unroll
            for (int r = 0; r < 4; r++) cp[(size_t)r * Fdim] = acc[mi][ni][r];
        }
}

// ---------------- fallback fp32 GEMM (only if ws too small; insurance) ----------------
__global__ void gemm_f32_naive(const float* __restrict__ A, const float* __restrict__ W,
                               float* __restrict__ C) {
    int col = blockIdx.x * blockDim.x + threadIdx.x;
    int row = blockIdx.y;
    float s = 0.f;
    for (int k = 0; k < Fdim; k++) s += A[(size_t)row * Fdim + k] * W[(size_t)col * Fdim + k];
    C[(size_t)row * Fdim + col] = s;
}

// ---------------- kernel 3: LIF scan, in-place, full-unroll deep-ILP (unchanged) ------
__global__ __launch_bounds__(256, 1) void lif_kernel(float* __restrict__ gs,
                                                     const float* __restrict__ bias) {
    int idx = blockIdx.x * blockDim.x + threadIdx.x;   // b*F + f
    int b = idx >> 11, f = idx & (Fdim - 1);
    const float bf = bias[f];
    float* p = gs + (size_t)b * Tdim * Fdim + f;

    float g[Tdim];
#pragma unroll
    for (int t = 0; t < Tdim; t++) g[t] = p[(size_t)t * Fdim];

    float v = 0.f;
#pragma unroll
    for (int t = 0; t < Tdim; t++) {
        float vn = v + 0.01f * ((0.0f - v) + (g[t] + bf));
        float z = (vn > 1.0f) ? 1.0f : 0.0f;
        v = vn - z;                    // subtractive reset (V_TH = 1)
        p[(size_t)t * Fdim] = z;
    }
}

extern "C" void kernel_launch(void* const* d_in, const int* in_sizes, int n_in,
                              void* d_out, int out_size, void* d_ws, size_t ws_size,
                              hipStream_t stream) {
    const float* inp  = (const float*)d_in[0];
    const float* W    = (const float*)d_in[1];
    const float* bias = (const float*)d_in[2];
    float* out = (float*)d_out;

    const size_t needA = (size_t)Mdim * Fdim * 2;   // 16.8 MB
    const size_t needW = (size_t)Fdim * Fdim * 2;   //  8.4 MB

    if (ws_size >= needA + needW) {
        unsigned short* a16 = (unsigned short*)d_ws;
        unsigned short* w16 = (unsigned short*)((char*)d_ws + needA);
        convert_kernel<<<2048, 256, 0, stream>>>(inp, W, a16, w16);
        dim3 grid(Fdim / BN, Mdim / BM);            // (32, 32) = 1024 blocks
        gemm_kernel<<<grid, 256, 0, stream>>>(a16, w16, out);
    } else {
        dim3 grid(Fdim / 256, Mdim);
        gemm_f32_naive<<<grid, 256, 0, stream>>>(inp, W, out);
    }
    lif_kernel<<<(Bdim * Fdim) / 256, 256, 0, stream>>>(out, bias);
}

// Round 8
// 139.821 us; speedup vs baseline: 1.2219x; 1.2219x over previous
//
#include <hip/hip_runtime.h>
#include <hip/hip_bf16.h>
#include <stdint.h>

#define Bdim 32
#define Tdim 128
#define Fdim 2048
#define Mdim (Bdim*Tdim)   // 4096

#define BM 128
#define BN 128
#define BK 64

typedef __attribute__((ext_vector_type(8))) short bf16x8;
typedef __attribute__((ext_vector_type(4))) float f32x4;

__device__ inline unsigned short f2bf(float f) {
    union { float f; unsigned u; } x; x.f = f;
    unsigned r = (x.u + 0x7fffu + ((x.u >> 16) & 1u)) >> 16;   // RNE
    return (unsigned short)r;
}

// ---------------- kernel 1: fp32 -> bf16 convert (input and W) ----------------
__global__ void convert_kernel(const float* __restrict__ A, const float* __restrict__ W,
                               unsigned short* __restrict__ a16, unsigned short* __restrict__ w16) {
    const int nA4 = (Mdim * Fdim) / 4;   // 2097152
    const int nW4 = (Fdim * Fdim) / 4;   // 1048576
    const int stride = gridDim.x * blockDim.x;
    for (int i = blockIdx.x * blockDim.x + threadIdx.x; i < nA4 + nW4; i += stride) {
        const float4* src; unsigned short* dst; int j;
        if (i < nA4) { src = (const float4*)A; dst = a16; j = i; }
        else         { src = (const float4*)W; dst = w16; j = i - nA4; }
        float4 v = src[j];
        ushort4 o;
        o.x = f2bf(v.x); o.y = f2bf(v.y); o.z = f2bf(v.z); o.w = f2bf(v.w);
        *(ushort4*)(dst + 4 * (size_t)j) = o;
    }
}

// ------- kernel 2: bf16 MFMA GEMM (R6 loop, verified 0-conflict) + fused LIF epilogue ----
// C[M,N] = A[M,K]*W[N,K]^T; row m = b*128+t, so blockIdx.y's 128-row tile is ALL timesteps
// of batch b => LIF scan runs in-block off an LDS-staged C-tile. d_out receives z directly.
__global__ __launch_bounds__(256) void gemm_fused_kernel(const unsigned short* __restrict__ A,
                                                         const unsigned short* __restrict__ Wm,
                                                         const float* __restrict__ bias,
                                                         float* __restrict__ Z) {
    // union: staging (2x16KB A + 2x16KB B = 64KB) vs epilogue ctile 128x132 f32 (66KB)
    __shared__ __align__(16) char smem[128 * 132 * 4];

    const int tid = threadIdx.x;
    const int wid = tid >> 6, lane = tid & 63;
    const int wr = wid >> 1, wc = wid & 1;          // wave -> 64x64 quadrant
    const int m0 = blockIdx.y * BM, n0 = blockIdx.x * BN;

    f32x4 acc[4][4];
#pragma unroll
    for (int i = 0; i < 4; i++)
#pragma unroll
        for (int j = 0; j < 4; j++) acc[i][j] = f32x4{0.f, 0.f, 0.f, 0.f};

    const int frow = lane & 15;
    const int lgrp = lane >> 4;                     // 0..3: k-slot group

    // swizzle (verified 0 conflicts R6): row = 8 chunks of 16B; data chunk c of row r
    // stored at slot c^(r&7). LDS dest LINEAR (global_load_lds reqt), source pre-permuted.
    auto stage = [&](int buf, int kt) {
        const int k0 = kt * BK;
        char* sAb = smem + buf * 16384;
        char* sBb = smem + 32768 + buf * 16384;
#pragma unroll
        for (int j = 0; j < 4; ++j) {
            const int base = wid * 1024 + j * 4096;   // wave-uniform byte base in 16KB tile
            const int off  = base + lane * 16;
            const int row  = off >> 7;                // 128B per tile row
            const int chk  = (off & 127) >> 4;
            const int scol = ((chk ^ (row & 7)) << 3);
            const unsigned short* ga = A  + (size_t)(m0 + row) * Fdim + k0 + scol;
            const unsigned short* gb = Wm + (size_t)(n0 + row) * Fdim + k0 + scol;
            __builtin_amdgcn_global_load_lds(
                (const __attribute__((address_space(1))) void*)ga,
                (__attribute__((address_space(3))) void*)(sAb + base), 16, 0, 0);
            __builtin_amdgcn_global_load_lds(
                (const __attribute__((address_space(1))) void*)gb,
                (__attribute__((address_space(3))) void*)(sBb + base), 16, 0, 0);
        }
    };

    stage(0, 0);
    __syncthreads();

    int cur = 0;
    const int NT = Fdim / BK;                         // 32
    for (int kt = 0; kt < NT; ++kt) {
        if (kt + 1 < NT) stage(cur ^ 1, kt + 1);      // async prefetch overlaps compute

        const unsigned short* sAc = (const unsigned short*)(smem + cur * 16384);
        const unsigned short* sBc = (const unsigned short*)(smem + 32768 + cur * 16384);
        bf16x8 af[2][4], bfr[2][4];
#pragma unroll
        for (int kk = 0; kk < 2; kk++) {
            const int chunk = kk * 4 + lgrp;
#pragma unroll
            for (int mi = 0; mi < 4; mi++) {
                const int r = wr * 64 + mi * 16 + frow;
                af[kk][mi] = *(const bf16x8*)(sAc + r * BK + ((chunk ^ (r & 7)) << 3));
            }
#pragma unroll
            for (int ni = 0; ni < 4; ni++) {
                const int r = wc * 64 + ni * 16 + frow;
                bfr[kk][ni] = *(const bf16x8*)(sBc + r * BK + ((chunk ^ (r & 7)) << 3));
            }
        }
#pragma unroll
        for (int kk = 0; kk < 2; kk++)
#pragma unroll
            for (int mi = 0; mi < 4; mi++)
#pragma unroll
                for (int ni = 0; ni < 4; ni++)
                    acc[mi][ni] = __builtin_amdgcn_mfma_f32_16x16x32_bf16(af[kk][mi], bfr[kk][ni], acc[mi][ni], 0, 0, 0);

        __syncthreads();   // drain: prefetch landed, all reads of `cur` done
        cur ^= 1;
    }

    // ---- fused LIF epilogue ----
    // stage acc -> ctile[128][132] f32 (pad 132: 4-row groups 16 banks apart -> 2-way free)
    float* ct = (float*)smem;
#pragma unroll
    for (int mi = 0; mi < 4; mi++)
#pragma unroll
        for (int ni = 0; ni < 4; ni++) {
            const int r0 = wr * 64 + mi * 16 + (lane >> 4) * 4;
            const int c0 = wc * 64 + ni * 16 + (lane & 15);
#pragma unroll
            for (int r = 0; r < 4; r++) ct[(r0 + r) * 132 + c0] = acc[mi][ni][r];
        }
    __syncthreads();

    // scan over t (=tile row) per feature column; rows m0..m0+127 are t=0..127 of batch by
    if (tid < 128) {
        const int gcol = n0 + tid;
        const float bf = bias[gcol];
        float* outp = Z + (size_t)m0 * Fdim + gcol;
        float v = 0.f;
#pragma unroll 16
        for (int t = 0; t < Tdim; t++) {
            const float g = ct[t * 132 + tid] + bf;
            const float vn = v + 0.01f * ((0.0f - v) + g);
            const float z = (vn > 1.0f) ? 1.0f : 0.0f;
            v = vn - z;                    // subtractive reset (V_TH = 1)
            outp[(size_t)t * Fdim] = z;
        }
    }
}

// ---------------- fallback fp32 GEMM (only if ws too small; insurance) ----------------
__global__ void gemm_f32_naive(const float* __restrict__ A, const float* __restrict__ W,
                               float* __restrict__ C) {
    int col = blockIdx.x * blockDim.x + threadIdx.x;
    int row = blockIdx.y;
    float s = 0.f;
    for (int k = 0; k < Fdim; k++) s += A[(size_t)row * Fdim + k] * W[(size_t)col * Fdim + k];
    C[(size_t)row * Fdim + col] = s;
}

// ---------------- fallback LIF scan (only used with gemm_f32_naive path) --------------
__global__ __launch_bounds__(256, 1) void lif_kernel(float* __restrict__ gs,
                                                     const float* __restrict__ bias) {
    int idx = blockIdx.x * blockDim.x + threadIdx.x;   // b*F + f
    int b = idx >> 11, f = idx & (Fdim - 1);
    const float bf = bias[f];
    float* p = gs + (size_t)b * Tdim * Fdim + f;
    float v = 0.f;
#pragma unroll 16
    for (int t = 0; t < Tdim; t++) {
        float g = p[(size_t)t * Fdim] + bf;
        float vn = v + 0.01f * ((0.0f - v) + g);
        float z = (vn > 1.0f) ? 1.0f : 0.0f;
        v = vn - z;
        p[(size_t)t * Fdim] = z;
    }
}

extern "C" void kernel_launch(void* const* d_in, const int* in_sizes, int n_in,
                              void* d_out, int out_size, void* d_ws, size_t ws_size,
                              hipStream_t stream) {
    const float* inp  = (const float*)d_in[0];
    const float* W    = (const float*)d_in[1];
    const float* bias = (const float*)d_in[2];
    float* out = (float*)d_out;

    const size_t needA = (size_t)Mdim * Fdim * 2;   // 16.8 MB
    const size_t needW = (size_t)Fdim * Fdim * 2;   //  8.4 MB

    if (ws_size >= needA + needW) {
        unsigned short* a16 = (unsigned short*)d_ws;
        unsigned short* w16 = (unsigned short*)((char*)d_ws + needA);
        convert_kernel<<<2048, 256, 0, stream>>>(inp, W, a16, w16);
        dim3 grid(Fdim / BN, Mdim / BM);            // (16, 32) = 512 blocks
        gemm_fused_kernel<<<grid, 256, 0, stream>>>(a16, w16, bias, out);
    } else {
        dim3 grid(Fdim / 256, Mdim);
        gemm_f32_naive<<<grid, 256, 0, stream>>>(inp, W, out);
        lif_kernel<<<(Bdim * Fdim) / 256, 256, 0, stream>>>(out, bias);
    }
}

// Round 9
// 134.349 us; speedup vs baseline: 1.2717x; 1.0407x over previous
//
#include <hip/hip_runtime.h>
#include <hip/hip_bf16.h>
#include <stdint.h>

#define Bdim 32
#define Tdim 128
#define Fdim 2048
#define Mdim (Bdim*Tdim)   // 4096

#define BM 256
#define BN 128
#define BK 64
#define NT (Fdim/BK)       // 32

typedef __attribute__((ext_vector_type(8))) short bf16x8;
typedef __attribute__((ext_vector_type(4))) float f32x4;

__device__ inline unsigned short f2bf(float f) {
    union { float f; unsigned u; } x; x.f = f;
    unsigned r = (x.u + 0x7fffu + ((x.u >> 16) & 1u)) >> 16;   // RNE
    return (unsigned short)r;
}

// ---------------- kernel 1: fp32 -> bf16 convert (input and W) ----------------
__global__ void convert_kernel(const float* __restrict__ A, const float* __restrict__ W,
                               unsigned short* __restrict__ a16, unsigned short* __restrict__ w16) {
    const int nA4 = (Mdim * Fdim) / 4;   // 2097152
    const int nW4 = (Fdim * Fdim) / 4;   // 1048576
    const int stride = gridDim.x * blockDim.x;
    for (int i = blockIdx.x * blockDim.x + threadIdx.x; i < nA4 + nW4; i += stride) {
        const float4* src; unsigned short* dst; int j;
        if (i < nA4) { src = (const float4*)A; dst = a16; j = i; }
        else         { src = (const float4*)W; dst = w16; j = i - nA4; }
        float4 v = src[j];
        ushort4 o;
        o.x = f2bf(v.x); o.y = f2bf(v.y); o.z = f2bf(v.z); o.w = f2bf(v.w);
        *(ushort4*)(dst + 4 * (size_t)j) = o;
    }
}

// ------- kernel 2: 256x128-tile bf16 GEMM, triple-buffer distance-2 counted-vmcnt
//         pipeline (T4) + verified 0-conflict XOR swizzle (T2) + fused LIF epilogue ----
// 512 threads = 8 waves (4M x 2N, 64x64 out each). Grid 16x16=256 = 1 block/CU.
// LDS: 3 slabs x 48KB (A 32KB + B 16KB); epilogue ctile 256x132 f32 = 135KB overlays.
// Pipeline: stage(t) issued at iter t-2; iter t = {vmcnt(6) [own 6 loads of stage(t)
// done; stage(t+1)'s 6 stay in flight], s_barrier [all waves' stage(t) visible],
// stage(t+2) [writes buf (t-1)%3, safe: everyone finished reading it before their
// barrier arrival], ds_read buf t%3, 32 MFMA}. Final iter peels to vmcnt(0).
__global__ __launch_bounds__(512, 2) void gemm_fused_kernel(const unsigned short* __restrict__ A,
                                                            const unsigned short* __restrict__ Wm,
                                                            const float* __restrict__ bias,
                                                            float* __restrict__ Z) {
    __shared__ __align__(16) char smem[147456];   // max(3*49152, 256*132*4)

    const int tid = threadIdx.x;
    const int wid = tid >> 6, lane = tid & 63;
    const int wr = wid >> 1, wc = wid & 1;          // wave -> 64x64 sub-tile of 256x128
    const int m0 = blockIdx.y * BM, n0 = blockIdx.x * BN;

    f32x4 acc[4][4];
#pragma unroll
    for (int i = 0; i < 4; i++)
#pragma unroll
        for (int j = 0; j < 4; j++) acc[i][j] = f32x4{0.f, 0.f, 0.f, 0.f};

    const int frow = lane & 15;
    const int lgrp = lane >> 4;                     // 0..3: k-slot group

    // swizzle (R6-verified 0 conflicts): row = 8 chunks of 16B; data chunk c of row r
    // stored at slot c^(r&7). LDS dest LINEAR (global_load_lds reqt), source pre-permuted.
    // 6 global_load_lds per wave per stage (4 A + 2 B) -> vmcnt counts in units of 6.
    auto stage = [&](int buf, int kt) {
        const int k0 = kt * BK;
        char* sAb = smem + buf * 49152;
        char* sBb = sAb + 32768;
#pragma unroll
        for (int j = 0; j < 4; ++j) {                 // A: 32KB = 32 chunks, 4/wave
            const int base = wid * 4096 + j * 1024;
            const int off  = base + lane * 16;
            const int row  = off >> 7;                // 128B per tile row (0..255)
            const int chk  = (off & 127) >> 4;
            const int scol = (chk ^ (row & 7)) << 3;
            const unsigned short* ga = A + (size_t)(m0 + row) * Fdim + k0 + scol;
            __builtin_amdgcn_global_load_lds(
                (const __attribute__((address_space(1))) void*)ga,
                (__attribute__((address_space(3))) void*)(sAb + base), 16, 0, 0);
        }
#pragma unroll
        for (int j = 0; j < 2; ++j) {                 // B: 16KB = 16 chunks, 2/wave
            const int base = wid * 2048 + j * 1024;
            const int off  = base + lane * 16;
            const int row  = off >> 7;                // 0..127
            const int chk  = (off & 127) >> 4;
            const int scol = (chk ^ (row & 7)) << 3;
            const unsigned short* gb = Wm + (size_t)(n0 + row) * Fdim + k0 + scol;
            __builtin_amdgcn_global_load_lds(
                (const __attribute__((address_space(1))) void*)gb,
                (__attribute__((address_space(3))) void*)(sBb + base), 16, 0, 0);
        }
    };

    stage(0, 0);
    stage(1, 1);

#pragma unroll 1
    for (int t = 0; t < NT; ++t) {
        if (t < NT - 1) asm volatile("s_waitcnt vmcnt(6)" ::: "memory");
        else            asm volatile("s_waitcnt vmcnt(0)" ::: "memory");
        __builtin_amdgcn_s_barrier();
        __builtin_amdgcn_sched_barrier(0);            // nothing hoists above the barrier
        if (t + 2 < NT) stage((t + 2) % 3, t + 2);

        const unsigned short* sAc = (const unsigned short*)(smem + (t % 3) * 49152);
        const unsigned short* sBc = (const unsigned short*)(smem + (t % 3) * 49152 + 32768);
        bf16x8 af[2][4], bfr[2][4];
#pragma unroll
        for (int kk = 0; kk < 2; kk++) {
            const int chunk = kk * 4 + lgrp;
#pragma unroll
            for (int mi = 0; mi < 4; mi++) {
                const int r = wr * 64 + mi * 16 + frow;
                af[kk][mi] = *(const bf16x8*)(sAc + r * BK + ((chunk ^ (r & 7)) << 3));
            }
#pragma unroll
            for (int ni = 0; ni < 4; ni++) {
                const int r = wc * 64 + ni * 16 + frow;
                bfr[kk][ni] = *(const bf16x8*)(sBc + r * BK + ((chunk ^ (r & 7)) << 3));
            }
        }
#pragma unroll
        for (int kk = 0; kk < 2; kk++)
#pragma unroll
            for (int mi = 0; mi < 4; mi++)
#pragma unroll
                for (int ni = 0; ni < 4; ni++)
                    acc[mi][ni] = __builtin_amdgcn_mfma_f32_16x16x32_bf16(af[kk][mi], bfr[kk][ni], acc[mi][ni], 0, 0, 0);
    }

    __syncthreads();   // full drain; all waves done with staging buffers

    // ---- fused LIF epilogue ----
    // acc -> ctile[256][132] f32 (pad 132: +4-row groups land 16 banks apart -> 2-way free)
    float* ct = (float*)smem;
#pragma unroll
    for (int mi = 0; mi < 4; mi++)
#pragma unroll
        for (int ni = 0; ni < 4; ni++) {
            const int r0 = wr * 64 + mi * 16 + (lane >> 4) * 4;
            const int c0 = wc * 64 + ni * 16 + (lane & 15);
#pragma unroll
            for (int r = 0; r < 4; r++) ct[(r0 + r) * 132 + c0] = acc[mi][ni][r];
        }
    __syncthreads();

    // rows m0..m0+255 = batches 2*by, 2*by+1 (t = row & 127). 256 scan chains, tid<256.
    if (tid < 256) {
        const int sub  = tid >> 7;                   // which of the 2 batches in this tile
        const int col  = tid & 127;
        const int gcol = n0 + col;
        const float bf = bias[gcol];
        float* outp = Z + (size_t)(m0 + sub * 128) * Fdim + gcol;
        float v = 0.f;
#pragma unroll 16
        for (int t = 0; t < Tdim; t++) {
            const float g = ct[(sub * 128 + t) * 132 + col] + bf;
            const float vn = v + 0.01f * ((0.0f - v) + g);
            const float z = (vn > 1.0f) ? 1.0f : 0.0f;
            v = vn - z;                    // subtractive reset (V_TH = 1)
            outp[(size_t)t * Fdim] = z;
        }
    }
}

// ---------------- fallback fp32 GEMM (only if ws too small; insurance) ----------------
__global__ void gemm_f32_naive(const float* __restrict__ A, const float* __restrict__ W,
                               float* __restrict__ C) {
    int col = blockIdx.x * blockDim.x + threadIdx.x;
    int row = blockIdx.y;
    float s = 0.f;
    for (int k = 0; k < Fdim; k++) s += A[(size_t)row * Fdim + k] * W[(size_t)col * Fdim + k];
    C[(size_t)row * Fdim + col] = s;
}

// ---------------- fallback LIF scan (only used with gemm_f32_naive path) --------------
__global__ __launch_bounds__(256, 1) void lif_kernel(float* __restrict__ gs,
                                                     const float* __restrict__ bias) {
    int idx = blockIdx.x * blockDim.x + threadIdx.x;   // b*F + f
    int b = idx >> 11, f = idx & (Fdim - 1);
    const float bf = bias[f];
    float* p = gs + (size_t)b * Tdim * Fdim + f;
    float v = 0.f;
#pragma unroll 16
    for (int t = 0; t < Tdim; t++) {
        float g = p[(size_t)t * Fdim] + bf;
        float vn = v + 0.01f * ((0.0f - v) + g);
        float z = (vn > 1.0f) ? 1.0f : 0.0f;
        v = vn - z;
        p[(size_t)t * Fdim] = z;
    }
}

extern "C" void kernel_launch(void* const* d_in, const int* in_sizes, int n_in,
                              void* d_out, int out_size, void* d_ws, size_t ws_size,
                              hipStream_t stream) {
    const float* inp  = (const float*)d_in[0];
    const float* W    = (const float*)d_in[1];
    const float* bias = (const float*)d_in[2];
    float* out = (float*)d_out;

    const size_t needA = (size_t)Mdim * Fdim * 2;   // 16.8 MB
    const size_t needW = (size_t)Fdim * Fdim * 2;   //  8.4 MB

    if (ws_size >= needA + needW) {
        unsigned short* a16 = (unsigned short*)d_ws;
        unsigned short* w16 = (unsigned short*)((char*)d_ws + needA);
        convert_kernel<<<2048, 256, 0, stream>>>(inp, W, a16, w16);
        dim3 grid(Fdim / BN, Mdim / BM);            // (16, 16) = 256 blocks = 1/CU
        gemm_fused_kernel<<<grid, 512, 0, stream>>>(a16, w16, bias, out);
    } else {
        dim3 grid(Fdim / 256, Mdim);
        gemm_f32_naive<<<grid, 256, 0, stream>>>(inp, W, out);
        lif_kernel<<<(Bdim * Fdim) / 256, 256, 0, stream>>>(out, bias);
    }
}